// Round 7
// baseline (298.470 us; speedup 1.0000x reference)
//
#include <hip/hip_runtime.h>
#include <cstddef>

// ---------------------------------------------------------------------------
// SAGEBlock: 3-layer GraphSAGE (mean aggr), N=50000, E=800000.
//   h1 = relu(agg(x)@Wl1 + x@Wr1 + b1)              128 -> 256
//   h2 = relu(agg(h1@Wl2) + h1@Wr2 + b2)            256 -> 128
//   out= sigmoid(agg(h2@Wl3) + h2@Wr3 + b3)         128 -> 64
// R7: bucketed 2-pass CSR build. k_fill's random 4B scatter paid a 64B write
//     granule per edge (55MB writeback for 3.2MB data). Pass1 scatters packed
//     (src|ln) 4B into per-bucket (16-node) windows (~1KB locality); pass2 is
//     one WG per bucket: dense read, LDS fill counters, dense single-XCD write.
// ---------------------------------------------------------------------------

using frag  = __attribute__((ext_vector_type(8))) short;   // 8 bf16
using f32x4 = __attribute__((ext_vector_type(4))) float;

__device__ __forceinline__ ushort f2bf(float f) {
    union { float f; unsigned u; } v; v.f = f;
    unsigned r = v.u + 0x7FFF + ((v.u >> 16) & 1);   // RNE
    return (ushort)(r >> 16);
}
__device__ __forceinline__ float bf2f(ushort u) {
    union { unsigned u; float f; } v; v.u = ((unsigned)u) << 16;
    return v.f;
}

// ---------------- CSR build ----------------

__global__ void k_degree(const int* __restrict__ dst, int* __restrict__ deg, int E) {
    int e = blockIdx.x * blockDim.x + threadIdx.x;
    if (e < E) atomicAdd(&deg[dst[e]], 1);
}

__global__ void k_scan1(const int* __restrict__ deg, int* __restrict__ excl,
                        int* __restrict__ bsum, int n) {
    __shared__ int sh[1024];
    int t = threadIdx.x;
    int i = blockIdx.x * 1024 + t;
    int v = (i < n) ? deg[i] : 0;
    sh[t] = v;
    __syncthreads();
    for (int off = 1; off < 1024; off <<= 1) {
        int add = (t >= off) ? sh[t - off] : 0;
        __syncthreads();
        sh[t] += add;
        __syncthreads();
    }
    if (i < n) excl[i] = sh[t] - v;
    if (t == 1023) bsum[blockIdx.x] = sh[t];
}

// also writes row_start[n] = E sentinel (total)
__global__ void k_scan2(int* __restrict__ bsum, int nb, int* __restrict__ row_start, int n) {
    if (blockIdx.x == 0 && threadIdx.x == 0) {
        int run = 0;
        for (int b = 0; b < nb; ++b) { int v = bsum[b]; bsum[b] = run; run += v; }
        row_start[n] = run;
    }
}

__global__ void k_scan3(int* __restrict__ row_start, const int* __restrict__ bsum, int n) {
    int i = blockIdx.x * blockDim.x + threadIdx.x;
    if (i < n) row_start[i] += bsum[i >> 10];
}

// pass 1: scatter packed (src | (dst&15)<<16) into bucket window
// bucket b = dst>>4 spans CSR range [row_start[b*16], row_start[b*16+16])
__global__ void k_bucket(const int* __restrict__ src, const int* __restrict__ dst,
                         const int* __restrict__ row_start, int* __restrict__ bfill,
                         unsigned* __restrict__ pairs, int E) {
    int e = blockIdx.x * blockDim.x + threadIdx.x;
    if (e < E) {
        int d = dst[e];
        int b = d >> 4;
        int base = row_start[d & ~15];
        int p = base + atomicAdd(&bfill[b], 1);
        pairs[p] = (unsigned)src[e] | ((unsigned)(d & 15) << 16);
    }
}

// pass 2: one workgroup per bucket; dense read of its window, LDS fill
// counters, dense write of csr_src into the same exclusive window.
__global__ __launch_bounds__(256)
void k_fill2(const unsigned* __restrict__ pairs, const int* __restrict__ row_start,
             int* __restrict__ csr_src, int M) {
    __shared__ int lrs[17];
    __shared__ int lfill[16];
    int n0 = blockIdx.x * 16;
    int t = threadIdx.x;
    if (t < 17) {
        int idx = n0 + t; if (idx > M) idx = M;
        lrs[t] = row_start[idx];
    }
    if (t < 16) lfill[t] = 0;
    __syncthreads();
    int s = lrs[0];
    int ne = lrs[16] - s;
    for (int i = t; i < ne; i += 256) {
        unsigned pk = pairs[s + i];
        int ln = pk >> 16;
        int pos = lrs[ln] + atomicAdd(&lfill[ln], 1);
        csr_src[pos] = (int)(pk & 0xFFFFu);
    }
}

// ---------------- dtype converts ----------------

__global__ void k_cvt_x(const float* __restrict__ in, ushort* __restrict__ out, int n4) {
    int i = blockIdx.x * blockDim.x + threadIdx.x;
    if (i < n4) {
        float4 v = ((const float4*)in)[i];
        ushort4 o; o.x = f2bf(v.x); o.y = f2bf(v.y); o.z = f2bf(v.z); o.w = f2bf(v.w);
        ((ushort4*)out)[i] = o;
    }
}

struct CvtDesc {
    const float* s[6];
    ushort*      d[6];
    int K[6];
    int N[6];
};

__global__ void k_cvt_w6(CvtDesc c) {
    int wi = blockIdx.y;
    int t = blockIdx.x * blockDim.x + threadIdx.x;
    int K = c.K[wi], N = c.N[wi];
    if (t < K * N) {
        int k = t / N, n = t % N;
        c.d[wi][(size_t)n * K + k] = f2bf(c.s[wi][t]);
    }
}

// ---------------- mean aggregation + fused epilogue ----------------
// EPI: 0 = plain bf16 out; 1 = relu(agg+u+b) bf16 out; 2 = sigmoid(agg+u+b) f32 out

template <int F, int EPI>
__global__ __launch_bounds__(256)
void agg_bf(const ushort* __restrict__ in, const int* __restrict__ csr_src,
            const int* __restrict__ row_start, const int* __restrict__ deg,
            const ushort* __restrict__ u, const float* __restrict__ bias,
            void* __restrict__ out, int nN) {
    int node = blockIdx.x * 4 + (threadIdx.x >> 6);
    if (node >= nN) return;
    int lane = threadIdx.x & 63;
    constexpr int EPL = F / 64;               // 1 or 2
    int start = row_start[node];
    int d = deg[node];
    float acc0 = 0.f, acc1 = 0.f;

    auto gat = [&](int j, int q) {
        int s = csr_src[start + j + q];
        if constexpr (EPL == 2) {
            ushort2 uv = *(const ushort2*)(in + (size_t)s * F + lane * 2);
            acc0 += bf2f(uv.x); acc1 += bf2f(uv.y);
        } else {
            acc0 += bf2f(in[(size_t)s * F + lane]);
        }
    };

    int j = 0;
    for (; j + 8 <= d; j += 8) {
        gat(j,0); gat(j,1); gat(j,2); gat(j,3);
        gat(j,4); gat(j,5); gat(j,6); gat(j,7);
    }
    for (; j + 2 <= d; j += 2) { gat(j,0); gat(j,1); }
    for (; j < d; ++j) gat(j,0);

    float inv = 1.f / (float)(d > 0 ? d : 1);
    acc0 *= inv; acc1 *= inv;

    if constexpr (EPI == 0) {
        if constexpr (EPL == 2) {
            ushort2 o; o.x = f2bf(acc0); o.y = f2bf(acc1);
            *(ushort2*)((ushort*)out + (size_t)node * F + lane * 2) = o;
        } else {
            ((ushort*)out)[(size_t)node * F + lane] = f2bf(acc0);
        }
    } else if constexpr (EPL == 2) {
        ushort2 uv = *(const ushort2*)(u + (size_t)node * F + lane * 2);
        acc0 += bf2f(uv.x) + bias[lane * 2];
        acc1 += bf2f(uv.y) + bias[lane * 2 + 1];
        if constexpr (EPI == 1) {
            ushort2 o; o.x = f2bf(fmaxf(acc0, 0.f)); o.y = f2bf(fmaxf(acc1, 0.f));
            *(ushort2*)((ushort*)out + (size_t)node * F + lane * 2) = o;
        } else {
            float2 o; o.x = 1.f / (1.f + __expf(-acc0)); o.y = 1.f / (1.f + __expf(-acc1));
            *(float2*)((float*)out + (size_t)node * F + lane * 2) = o;
        }
    } else {
        float v = acc0 + bf2f(u[(size_t)node * F + lane]) + bias[lane];
        if constexpr (EPI == 1) {
            ((ushort*)out)[(size_t)node * F + lane] = f2bf(fmaxf(v, 0.f));
        } else {
            ((float*)out)[(size_t)node * F + lane] = 1.f / (1.f + __expf(-v));
        }
    }
}

// ---------------- bf16 MFMA GEMM (BK=64 loop), split-output epilogue --------
// C[M,N] = act( A1@B1^T (+ A2@B2^T) (+ bias) ); col < nsplit -> C1, else C2.
// A: [M][K] bf16. B: [N][K] bf16 (pre-transposed). LDS XOR-swizzled.

template <int BM, int BN, int WM, int WN, int ACT>
__global__ __launch_bounds__(WM * WN * 64)
void mgemm(const ushort* __restrict__ A1, const ushort* __restrict__ B1, int K1,
           const ushort* __restrict__ A2, const ushort* __restrict__ B2, int K2,
           const float* __restrict__ bias,
           ushort* __restrict__ C1, int ld1,
           ushort* __restrict__ C2, int ld2, int nsplit,
           int M, int N) {
    constexpr int NT = WM * WN * 64;
    constexpr int MF = BM / (WM * 16);
    constexpr int NF = BN / (WN * 16);
    __shared__ char lds[(BM + BN) * 128];     // rows x 64 bf16
    char* As = lds;
    char* Bs = lds + BM * 128;

    const int tid  = threadIdx.x;
    const int lane = tid & 63;
    const int wid  = tid >> 6;
    const int wm   = wid % WM, wn = wid / WM;
    const int bm   = blockIdx.x * BM;
    const int bn   = blockIdx.y * BN;
    const int l15  = lane & 15;
    const int lhi  = lane >> 4;

    f32x4 acc[MF][NF] = {};

    for (int pass = 0; pass < 2; ++pass) {
        const ushort* A = pass ? A2 : A1;
        const ushort* B = pass ? B2 : B1;
        const int K = pass ? K2 : K1;
        if (A == nullptr) continue;
        for (int k0 = 0; k0 < K; k0 += 64) {
            #pragma unroll
            for (int it = 0; it < BM * 8 / NT; ++it) {       // stage A
                int flat = it * NT + tid;
                int row = flat >> 3;
                int cb = (flat & 7) * 16;
                frag v = {};
                int gr = bm + row;
                if (gr < M) v = *(const frag*)(A + (size_t)gr * K + k0 + (flat & 7) * 8);
                *(frag*)(As + row * 128 + (cb ^ ((row & 7) << 4))) = v;
            }
            #pragma unroll
            for (int it = 0; it < BN * 8 / NT; ++it) {       // stage B
                int flat = it * NT + tid;
                int row = flat >> 3;
                int cb = (flat & 7) * 16;
                frag v = *(const frag*)(B + (size_t)(bn + row) * K + k0 + (flat & 7) * 8);
                *(frag*)(Bs + row * 128 + (cb ^ ((row & 7) << 4))) = v;
            }
            __syncthreads();
            #pragma unroll
            for (int ks = 0; ks < 2; ++ks) {
                const int kb = ks * 64 + lhi * 16;
                frag a[MF], b[NF];
                #pragma unroll
                for (int mf = 0; mf < MF; ++mf) {
                    int row = wm * MF * 16 + mf * 16 + l15;
                    a[mf] = *(const frag*)(As + row * 128 + (kb ^ ((row & 7) << 4)));
                }
                #pragma unroll
                for (int nf = 0; nf < NF; ++nf) {
                    int row = wn * NF * 16 + nf * 16 + l15;
                    b[nf] = *(const frag*)(Bs + row * 128 + (kb ^ ((row & 7) << 4)));
                }
                #pragma unroll
                for (int mf = 0; mf < MF; ++mf)
                    #pragma unroll
                    for (int nf = 0; nf < NF; ++nf)
                        acc[mf][nf] = __builtin_amdgcn_mfma_f32_16x16x32_bf16(
                            a[mf], b[nf], acc[mf][nf], 0, 0, 0);
            }
            __syncthreads();
        }
    }

    #pragma unroll
    for (int mf = 0; mf < MF; ++mf) {
        #pragma unroll
        for (int r = 0; r < 4; ++r) {
            int gm = bm + wm * MF * 16 + mf * 16 + lhi * 4 + r;
            if (gm >= M) continue;
            #pragma unroll
            for (int nf = 0; nf < NF; ++nf) {
                int gn = bn + wn * NF * 16 + nf * 16 + l15;
                float v = acc[mf][nf][r];
                if (bias) v += bias[gn];
                if (ACT == 1) v = fmaxf(v, 0.f);
                ushort o = f2bf(v);
                if (gn < nsplit) C1[(size_t)gm * ld1 + gn] = o;
                else             C2[(size_t)gm * ld2 + (gn - nsplit)] = o;
            }
        }
    }
}

// ---------------------------------------------------------------------------

extern "C" void kernel_launch(void* const* d_in, const int* in_sizes, int n_in,
                              void* d_out, int out_size, void* d_ws, size_t ws_size,
                              hipStream_t stream) {
    const float* x   = (const float*)d_in[0];
    const int*   ei  = (const int*)d_in[1];
    const float* Wl1 = (const float*)d_in[2];
    const float* Wr1 = (const float*)d_in[3];
    const float* b1  = (const float*)d_in[4];
    const float* Wl2 = (const float*)d_in[5];
    const float* Wr2 = (const float*)d_in[6];
    const float* b2  = (const float*)d_in[7];
    const float* Wl3 = (const float*)d_in[8];
    const float* Wr3 = (const float*)d_in[9];
    const float* b3  = (const float*)d_in[10];

    const int M = in_sizes[0] / 128;   // 50000
    const int E = in_sizes[1] / 2;     // 800000
    const int NBK = (M + 15) / 16;     // 3125 buckets of 16 nodes
    const int* src = ei;
    const int* dst = ei + E;

    char* w = (char*)d_ws;
    auto alloc = [&](size_t bytes) -> void* {
        void* p = (void*)w;
        w += (bytes + 255) & ~(size_t)255;
        return p;
    };
    int* deg       = (int*)alloc((size_t)M * 4);      // deg+bfill adjacent: one memset
    int* bfill     = (int*)alloc((size_t)NBK * 4);
    int* row_start = (int*)alloc((size_t)(M + 1) * 4);
    int* bsum      = (int*)alloc(256 * 4);
    unsigned* pairs = (unsigned*)alloc((size_t)E * 4);
    int* csr_src   = (int*)alloc((size_t)E * 4);
    ushort* Wl1t   = (ushort*)alloc(256 * 128 * 2);       // [256][128]
    ushort* Wr1t   = (ushort*)alloc(256 * 128 * 2);       // [256][128]
    ushort* Wcat2T = (ushort*)alloc(256 * 256 * 2);       // [256][256]: Wl2|Wr2 rows
    ushort* Wcat3T = (ushort*)alloc(128 * 128 * 2);       // [128][128]: Wl3|Wr3 rows
    ushort* bufA = (ushort*)alloc((size_t)M * 128 * 2);   // x_bf -> t2 -> t3
    ushort* bufB = (ushort*)alloc((size_t)M * 128 * 2);   // aggx -> h2
    ushort* bufH = (ushort*)alloc((size_t)M * 256 * 2);   // h1
    ushort* bufC = (ushort*)alloc((size_t)M * 128 * 2);   // u2 -> u3
    (void)ws_size; (void)n_in; (void)out_size;

    ushort* x_bf = bufA; ushort* t2 = bufA; ushort* t3 = bufA;
    ushort* aggx = bufB; ushort* h2 = bufB;
    ushort* h1 = bufH;
    ushort* u2 = bufC;   ushort* u3 = bufC;

    // one memset covers deg (padded to 256B) + bfill
    hipMemsetAsync(deg, 0, (((size_t)M * 4 + 255) & ~(size_t)255) + (size_t)NBK * 4, stream);

    // CSR build: degree -> scan (row_start, +E sentinel) -> bucket -> fill2
    k_degree<<<(E + 255) / 256, 256, 0, stream>>>(dst, deg, E);
    const int nb = (M + 1023) / 1024;
    k_scan1<<<nb, 1024, 0, stream>>>(deg, row_start, bsum, M);
    k_scan2<<<1, 64, 0, stream>>>(bsum, nb, row_start, M);
    k_scan3<<<(M + 255) / 256, 256, 0, stream>>>(row_start, bsum, M);
    k_bucket<<<(E + 255) / 256, 256, 0, stream>>>(src, dst, row_start, bfill, pairs, E);
    k_fill2<<<NBK, 256, 0, stream>>>(pairs, row_start, csr_src, M);

    // converts
    k_cvt_x<<<(M * 128 / 4 + 255) / 256, 256, 0, stream>>>(x, x_bf, M * 128 / 4);
    CvtDesc cd;
    cd.s[0] = Wl1; cd.d[0] = Wl1t;             cd.K[0] = 128; cd.N[0] = 256;
    cd.s[1] = Wr1; cd.d[1] = Wr1t;             cd.K[1] = 128; cd.N[1] = 256;
    cd.s[2] = Wl2; cd.d[2] = Wcat2T;           cd.K[2] = 256; cd.N[2] = 128;
    cd.s[3] = Wr2; cd.d[3] = Wcat2T + 128*256; cd.K[3] = 256; cd.N[3] = 128;
    cd.s[4] = Wl3; cd.d[4] = Wcat3T;           cd.K[4] = 128; cd.N[4] = 64;
    cd.s[5] = Wr3; cd.d[5] = Wcat3T + 64*128;  cd.K[5] = 128; cd.N[5] = 64;
    k_cvt_w6<<<dim3(128, 6), 256, 0, stream>>>(cd);

    const int gm64 = (M + 63) / 64;           // 782
    const int gagg = (M + 3) / 4;             // 12500

    // ---- layer 1: aggx = agg(x); h1 = relu(aggx@Wl1 + x@Wr1 + b1)
    agg_bf<128, 0><<<gagg, 256, 0, stream>>>(x_bf, csr_src, row_start, deg,
                                             nullptr, nullptr, aggx, M);
    mgemm<64, 64, 2, 2, 1><<<dim3(gm64, 4), 256, 0, stream>>>(
        aggx, Wl1t, 128, x_bf, Wr1t, 128, b1,
        h1, 256, nullptr, 0, 256, M, 256);

    // ---- layer 2: [t2|u2] = h1@Wcat2; h2 = relu(agg(t2) + u2 + b2)
    mgemm<64, 64, 2, 2, 0><<<dim3(gm64, 4), 256, 0, stream>>>(
        h1, Wcat2T, 256, nullptr, nullptr, 0, nullptr,
        t2, 128, u2, 128, 128, M, 256);
    agg_bf<128, 1><<<gagg, 256, 0, stream>>>(t2, csr_src, row_start, deg,
                                             u2, b2, h2, M);

    // ---- layer 3: [t3|u3] = h2@Wcat3; out = sigmoid(agg(t3) + u3 + b3)
    mgemm<64, 64, 2, 2, 0><<<dim3(gm64, 2), 256, 0, stream>>>(
        h2, Wcat3T, 128, nullptr, nullptr, 0, nullptr,
        t3, 64, u3, 64, 64, M, 128);
    agg_bf<64, 2><<<gagg, 256, 0, stream>>>(t3, csr_src, row_start, deg,
                                            u3, b3, (float*)d_out, M);
}

// Round 8
// 287.142 us; speedup vs baseline: 1.0395x; 1.0395x over previous
//
#include <hip/hip_runtime.h>
#include <cstddef>

// ---------------------------------------------------------------------------
// SAGEBlock: 3-layer GraphSAGE (mean aggr), N=50000, E=800000.
//   h1 = relu(agg(x)@Wl1 + x@Wr1 + b1)              128 -> 256
//   h2 = relu(agg(h1@Wl2) + h1@Wr2 + b2)            256 -> 128
//   out= sigmoid(agg(h2@Wl3) + h2@Wr3 + b3)         128 -> 64
// R8: CSR fill via packed 16-bit atomicOr. Plain 4B scatter stores streamed
//     to HBM un-merged (55MB for 3.2MB data, R6); bucketing hit atomic
//     contention (R7). atomicOr into a zeroed ushort array executes at the
//     shared memory point (no per-store line writeback), slots unique by
//     construction, bit-disjoint when sharing a word.
// ---------------------------------------------------------------------------

using frag  = __attribute__((ext_vector_type(8))) short;   // 8 bf16
using f32x4 = __attribute__((ext_vector_type(4))) float;

__device__ __forceinline__ ushort f2bf(float f) {
    union { float f; unsigned u; } v; v.f = f;
    unsigned r = v.u + 0x7FFF + ((v.u >> 16) & 1);   // RNE
    return (ushort)(r >> 16);
}
__device__ __forceinline__ float bf2f(ushort u) {
    union { unsigned u; float f; } v; v.u = ((unsigned)u) << 16;
    return v.f;
}

// ---------------- CSR build ----------------

__global__ void k_degree(const int* __restrict__ dst, int* __restrict__ deg, int E) {
    int e = blockIdx.x * blockDim.x + threadIdx.x;
    if (e < E) atomicAdd(&deg[dst[e]], 1);
}

__global__ void k_scan1(const int* __restrict__ deg, int* __restrict__ excl,
                        int* __restrict__ bsum, int n) {
    __shared__ int sh[1024];
    int t = threadIdx.x;
    int i = blockIdx.x * 1024 + t;
    int v = (i < n) ? deg[i] : 0;
    sh[t] = v;
    __syncthreads();
    for (int off = 1; off < 1024; off <<= 1) {
        int add = (t >= off) ? sh[t - off] : 0;
        __syncthreads();
        sh[t] += add;
        __syncthreads();
    }
    if (i < n) excl[i] = sh[t] - v;
    if (t == 1023) bsum[blockIdx.x] = sh[t];
}

__global__ void k_scan2(int* __restrict__ bsum, int nb) {
    if (blockIdx.x == 0 && threadIdx.x == 0) {
        int run = 0;
        for (int b = 0; b < nb; ++b) { int v = bsum[b]; bsum[b] = run; run += v; }
    }
}

__global__ void k_scan3(int* __restrict__ row_start, const int* __restrict__ bsum, int n) {
    int i = blockIdx.x * blockDim.x + threadIdx.x;
    if (i < n) row_start[i] += bsum[i >> 10];
}

// fill: unique slot p per edge (per-dst counter); write 16-bit src via atomicOr
__global__ void k_fill(const int* __restrict__ src, const int* __restrict__ dst,
                       const int* __restrict__ row_start, int* __restrict__ fill,
                       unsigned* __restrict__ csr16w, int E) {
    int e = blockIdx.x * blockDim.x + threadIdx.x;
    if (e < E) {
        int d = dst[e];
        int p = row_start[d] + atomicAdd(&fill[d], 1);
        atomicOr(&csr16w[p >> 1], (unsigned)src[e] << ((p & 1) * 16));
    }
}

// ---------------- dtype converts ----------------

__global__ void k_cvt_x(const float* __restrict__ in, ushort* __restrict__ out, int n4) {
    int i = blockIdx.x * blockDim.x + threadIdx.x;
    if (i < n4) {
        float4 v = ((const float4*)in)[i];
        ushort4 o; o.x = f2bf(v.x); o.y = f2bf(v.y); o.z = f2bf(v.z); o.w = f2bf(v.w);
        ((ushort4*)out)[i] = o;
    }
}

struct CvtDesc {
    const float* s[6];
    ushort*      d[6];
    int K[6];
    int N[6];
};

__global__ void k_cvt_w6(CvtDesc c) {
    int wi = blockIdx.y;
    int t = blockIdx.x * blockDim.x + threadIdx.x;
    int K = c.K[wi], N = c.N[wi];
    if (t < K * N) {
        int k = t / N, n = t % N;
        c.d[wi][(size_t)n * K + k] = f2bf(c.s[wi][t]);
    }
}

// ---------------- mean aggregation + fused epilogue ----------------
// EPI: 0 = plain bf16 out; 1 = relu(agg+u+b) bf16 out; 2 = sigmoid(agg+u+b) f32 out

template <int F, int EPI>
__global__ __launch_bounds__(256)
void agg_bf(const ushort* __restrict__ in, const ushort* __restrict__ csr16,
            const int* __restrict__ row_start, const int* __restrict__ deg,
            const ushort* __restrict__ u, const float* __restrict__ bias,
            void* __restrict__ out, int nN) {
    int node = blockIdx.x * 4 + (threadIdx.x >> 6);
    if (node >= nN) return;
    int lane = threadIdx.x & 63;
    constexpr int EPL = F / 64;               // 1 or 2
    int start = row_start[node];
    int d = deg[node];
    float acc0 = 0.f, acc1 = 0.f;

    auto gat = [&](int j, int q) {
        int s = csr16[start + j + q];
        if constexpr (EPL == 2) {
            ushort2 uv = *(const ushort2*)(in + (size_t)s * F + lane * 2);
            acc0 += bf2f(uv.x); acc1 += bf2f(uv.y);
        } else {
            acc0 += bf2f(in[(size_t)s * F + lane]);
        }
    };

    int j = 0;
    for (; j + 8 <= d; j += 8) {
        gat(j,0); gat(j,1); gat(j,2); gat(j,3);
        gat(j,4); gat(j,5); gat(j,6); gat(j,7);
    }
    for (; j + 2 <= d; j += 2) { gat(j,0); gat(j,1); }
    for (; j < d; ++j) gat(j,0);

    float inv = 1.f / (float)(d > 0 ? d : 1);
    acc0 *= inv; acc1 *= inv;

    if constexpr (EPI == 0) {
        if constexpr (EPL == 2) {
            ushort2 o; o.x = f2bf(acc0); o.y = f2bf(acc1);
            *(ushort2*)((ushort*)out + (size_t)node * F + lane * 2) = o;
        } else {
            ((ushort*)out)[(size_t)node * F + lane] = f2bf(acc0);
        }
    } else if constexpr (EPL == 2) {
        ushort2 uv = *(const ushort2*)(u + (size_t)node * F + lane * 2);
        acc0 += bf2f(uv.x) + bias[lane * 2];
        acc1 += bf2f(uv.y) + bias[lane * 2 + 1];
        if constexpr (EPI == 1) {
            ushort2 o; o.x = f2bf(fmaxf(acc0, 0.f)); o.y = f2bf(fmaxf(acc1, 0.f));
            *(ushort2*)((ushort*)out + (size_t)node * F + lane * 2) = o;
        } else {
            float2 o; o.x = 1.f / (1.f + __expf(-acc0)); o.y = 1.f / (1.f + __expf(-acc1));
            *(float2*)((float*)out + (size_t)node * F + lane * 2) = o;
        }
    } else {
        float v = acc0 + bf2f(u[(size_t)node * F + lane]) + bias[lane];
        if constexpr (EPI == 1) {
            ((ushort*)out)[(size_t)node * F + lane] = f2bf(fmaxf(v, 0.f));
        } else {
            ((float*)out)[(size_t)node * F + lane] = 1.f / (1.f + __expf(-v));
        }
    }
}

// ---------------- bf16 MFMA GEMM (BK=64 loop), split-output epilogue --------
// C[M,N] = act( A1@B1^T (+ A2@B2^T) (+ bias) ); col < nsplit -> C1, else C2.
// A: [M][K] bf16. B: [N][K] bf16 (pre-transposed). LDS XOR-swizzled.

template <int BM, int BN, int WM, int WN, int ACT>
__global__ __launch_bounds__(WM * WN * 64)
void mgemm(const ushort* __restrict__ A1, const ushort* __restrict__ B1, int K1,
           const ushort* __restrict__ A2, const ushort* __restrict__ B2, int K2,
           const float* __restrict__ bias,
           ushort* __restrict__ C1, int ld1,
           ushort* __restrict__ C2, int ld2, int nsplit,
           int M, int N) {
    constexpr int NT = WM * WN * 64;
    constexpr int MF = BM / (WM * 16);
    constexpr int NF = BN / (WN * 16);
    __shared__ char lds[(BM + BN) * 128];     // rows x 64 bf16
    char* As = lds;
    char* Bs = lds + BM * 128;

    const int tid  = threadIdx.x;
    const int lane = tid & 63;
    const int wid  = tid >> 6;
    const int wm   = wid % WM, wn = wid / WM;
    const int bm   = blockIdx.x * BM;
    const int bn   = blockIdx.y * BN;
    const int l15  = lane & 15;
    const int lhi  = lane >> 4;

    f32x4 acc[MF][NF] = {};

    for (int pass = 0; pass < 2; ++pass) {
        const ushort* A = pass ? A2 : A1;
        const ushort* B = pass ? B2 : B1;
        const int K = pass ? K2 : K1;
        if (A == nullptr) continue;
        for (int k0 = 0; k0 < K; k0 += 64) {
            #pragma unroll
            for (int it = 0; it < BM * 8 / NT; ++it) {       // stage A
                int flat = it * NT + tid;
                int row = flat >> 3;
                int cb = (flat & 7) * 16;
                frag v = {};
                int gr = bm + row;
                if (gr < M) v = *(const frag*)(A + (size_t)gr * K + k0 + (flat & 7) * 8);
                *(frag*)(As + row * 128 + (cb ^ ((row & 7) << 4))) = v;
            }
            #pragma unroll
            for (int it = 0; it < BN * 8 / NT; ++it) {       // stage B
                int flat = it * NT + tid;
                int row = flat >> 3;
                int cb = (flat & 7) * 16;
                frag v = *(const frag*)(B + (size_t)(bn + row) * K + k0 + (flat & 7) * 8);
                *(frag*)(Bs + row * 128 + (cb ^ ((row & 7) << 4))) = v;
            }
            __syncthreads();
            #pragma unroll
            for (int ks = 0; ks < 2; ++ks) {
                const int kb = ks * 64 + lhi * 16;
                frag a[MF], b[NF];
                #pragma unroll
                for (int mf = 0; mf < MF; ++mf) {
                    int row = wm * MF * 16 + mf * 16 + l15;
                    a[mf] = *(const frag*)(As + row * 128 + (kb ^ ((row & 7) << 4)));
                }
                #pragma unroll
                for (int nf = 0; nf < NF; ++nf) {
                    int row = wn * NF * 16 + nf * 16 + l15;
                    b[nf] = *(const frag*)(Bs + row * 128 + (kb ^ ((row & 7) << 4)));
                }
                #pragma unroll
                for (int mf = 0; mf < MF; ++mf)
                    #pragma unroll
                    for (int nf = 0; nf < NF; ++nf)
                        acc[mf][nf] = __builtin_amdgcn_mfma_f32_16x16x32_bf16(
                            a[mf], b[nf], acc[mf][nf], 0, 0, 0);
            }
            __syncthreads();
        }
    }

    #pragma unroll
    for (int mf = 0; mf < MF; ++mf) {
        #pragma unroll
        for (int r = 0; r < 4; ++r) {
            int gm = bm + wm * MF * 16 + mf * 16 + lhi * 4 + r;
            if (gm >= M) continue;
            #pragma unroll
            for (int nf = 0; nf < NF; ++nf) {
                int gn = bn + wn * NF * 16 + nf * 16 + l15;
                float v = acc[mf][nf][r];
                if (bias) v += bias[gn];
                if (ACT == 1) v = fmaxf(v, 0.f);
                ushort o = f2bf(v);
                if (gn < nsplit) C1[(size_t)gm * ld1 + gn] = o;
                else             C2[(size_t)gm * ld2 + (gn - nsplit)] = o;
            }
        }
    }
}

// ---------------------------------------------------------------------------

extern "C" void kernel_launch(void* const* d_in, const int* in_sizes, int n_in,
                              void* d_out, int out_size, void* d_ws, size_t ws_size,
                              hipStream_t stream) {
    const float* x   = (const float*)d_in[0];
    const int*   ei  = (const int*)d_in[1];
    const float* Wl1 = (const float*)d_in[2];
    const float* Wr1 = (const float*)d_in[3];
    const float* b1  = (const float*)d_in[4];
    const float* Wl2 = (const float*)d_in[5];
    const float* Wr2 = (const float*)d_in[6];
    const float* b2  = (const float*)d_in[7];
    const float* Wl3 = (const float*)d_in[8];
    const float* Wr3 = (const float*)d_in[9];
    const float* b3  = (const float*)d_in[10];

    const int M = in_sizes[0] / 128;   // 50000
    const int E = in_sizes[1] / 2;     // 800000
    const int* src = ei;
    const int* dst = ei + E;

    char* w = (char*)d_ws;
    auto alloc = [&](size_t bytes) -> void* {
        void* p = (void*)w;
        w += (bytes + 255) & ~(size_t)255;
        return p;
    };
    // deg, fill, csr16 contiguous -> single memset
    int* deg       = (int*)alloc((size_t)M * 4);
    int* fill      = (int*)alloc((size_t)M * 4);
    unsigned* csr16w = (unsigned*)alloc((size_t)E * 2);
    int* row_start = (int*)alloc((size_t)M * 4);
    int* bsum      = (int*)alloc(256 * 4);
    ushort* Wl1t   = (ushort*)alloc(256 * 128 * 2);       // [256][128]
    ushort* Wr1t   = (ushort*)alloc(256 * 128 * 2);       // [256][128]
    ushort* Wcat2T = (ushort*)alloc(256 * 256 * 2);       // [256][256]: Wl2|Wr2 rows
    ushort* Wcat3T = (ushort*)alloc(128 * 128 * 2);       // [128][128]: Wl3|Wr3 rows
    ushort* bufA = (ushort*)alloc((size_t)M * 128 * 2);   // x_bf -> t2 -> t3
    ushort* bufB = (ushort*)alloc((size_t)M * 128 * 2);   // aggx -> h2
    ushort* bufH = (ushort*)alloc((size_t)M * 256 * 2);   // h1
    ushort* bufC = (ushort*)alloc((size_t)M * 128 * 2);   // u2 -> u3
    (void)ws_size; (void)n_in; (void)out_size;

    const ushort* csr16 = (const ushort*)csr16w;
    ushort* x_bf = bufA; ushort* t2 = bufA; ushort* t3 = bufA;
    ushort* aggx = bufB; ushort* h2 = bufB;
    ushort* h1 = bufH;
    ushort* u2 = bufC;   ushort* u3 = bufC;

    // one memset covers deg + fill + csr16 (contiguous, pads included)
    hipMemsetAsync(deg, 0, (size_t)((char*)csr16w - (char*)deg) + (size_t)E * 2, stream);

    // CSR build
    k_degree<<<(E + 255) / 256, 256, 0, stream>>>(dst, deg, E);
    const int nb = (M + 1023) / 1024;
    k_scan1<<<nb, 1024, 0, stream>>>(deg, row_start, bsum, M);
    k_scan2<<<1, 64, 0, stream>>>(bsum, nb);
    k_scan3<<<(M + 255) / 256, 256, 0, stream>>>(row_start, bsum, M);
    k_fill<<<(E + 255) / 256, 256, 0, stream>>>(src, dst, row_start, fill, csr16w, E);

    // converts
    k_cvt_x<<<(M * 128 / 4 + 255) / 256, 256, 0, stream>>>(x, x_bf, M * 128 / 4);
    CvtDesc cd;
    cd.s[0] = Wl1; cd.d[0] = Wl1t;             cd.K[0] = 128; cd.N[0] = 256;
    cd.s[1] = Wr1; cd.d[1] = Wr1t;             cd.K[1] = 128; cd.N[1] = 256;
    cd.s[2] = Wl2; cd.d[2] = Wcat2T;           cd.K[2] = 256; cd.N[2] = 128;
    cd.s[3] = Wr2; cd.d[3] = Wcat2T + 128*256; cd.K[3] = 256; cd.N[3] = 128;
    cd.s[4] = Wl3; cd.d[4] = Wcat3T;           cd.K[4] = 128; cd.N[4] = 64;
    cd.s[5] = Wr3; cd.d[5] = Wcat3T + 64*128;  cd.K[5] = 128; cd.N[5] = 64;
    k_cvt_w6<<<dim3(128, 6), 256, 0, stream>>>(cd);

    const int gm64 = (M + 63) / 64;           // 782
    const int gagg = (M + 3) / 4;             // 12500

    // ---- layer 1: aggx = agg(x); h1 = relu(aggx@Wl1 + x@Wr1 + b1)
    agg_bf<128, 0><<<gagg, 256, 0, stream>>>(x_bf, csr16, row_start, deg,
                                             nullptr, nullptr, aggx, M);
    mgemm<64, 64, 2, 2, 1><<<dim3(gm64, 4), 256, 0, stream>>>(
        aggx, Wl1t, 128, x_bf, Wr1t, 128, b1,
        h1, 256, nullptr, 0, 256, M, 256);

    // ---- layer 2: [t2|u2] = h1@Wcat2; h2 = relu(agg(t2) + u2 + b2)
    mgemm<64, 64, 2, 2, 0><<<dim3(gm64, 4), 256, 0, stream>>>(
        h1, Wcat2T, 256, nullptr, nullptr, 0, nullptr,
        t2, 128, u2, 128, 128, M, 256);
    agg_bf<128, 1><<<gagg, 256, 0, stream>>>(t2, csr16, row_start, deg,
                                             u2, b2, h2, M);

    // ---- layer 3: [t3|u3] = h2@Wcat3; out = sigmoid(agg(t3) + u3 + b3)
    mgemm<64, 64, 2, 2, 0><<<dim3(gm64, 2), 256, 0, stream>>>(
        h2, Wcat3T, 128, nullptr, nullptr, 0, nullptr,
        t3, 64, u3, 64, 64, M, 128);
    agg_bf<64, 2><<<gagg, 256, 0, stream>>>(t3, csr16, row_start, deg,
                                            u3, b3, (float*)d_out, M);
}

// Round 9
// 287.111 us; speedup vs baseline: 1.0396x; 1.0001x over previous
//
#include <hip/hip_runtime.h>
#include <cstddef>

// ---------------------------------------------------------------------------
// SAGEBlock: 3-layer GraphSAGE (mean aggr), N=50000, E=800000.
//   h1 = relu(agg(x)@Wl1 + x@Wr1 + b1)              128 -> 256
//   h2 = relu(agg(h1@Wl2) + h1@Wr2 + b2)            256 -> 128
//   out= sigmoid(agg(h2@Wl3) + h2@Wr3 + b3)         128 -> 64
// R8: CSR fill via packed 16-bit atomicOr. Plain 4B scatter stores streamed
//     to HBM un-merged (55MB for 3.2MB data, R6); bucketing hit atomic
//     contention (R7). atomicOr into a zeroed ushort array executes at the
//     shared memory point (no per-store line writeback), slots unique by
//     construction, bit-disjoint when sharing a word.
// ---------------------------------------------------------------------------

using frag  = __attribute__((ext_vector_type(8))) short;   // 8 bf16
using f32x4 = __attribute__((ext_vector_type(4))) float;

__device__ __forceinline__ ushort f2bf(float f) {
    union { float f; unsigned u; } v; v.f = f;
    unsigned r = v.u + 0x7FFF + ((v.u >> 16) & 1);   // RNE
    return (ushort)(r >> 16);
}
__device__ __forceinline__ float bf2f(ushort u) {
    union { unsigned u; float f; } v; v.u = ((unsigned)u) << 16;
    return v.f;
}

// ---------------- CSR build ----------------

__global__ void k_degree(const int* __restrict__ dst, int* __restrict__ deg, int E) {
    int e = blockIdx.x * blockDim.x + threadIdx.x;
    if (e < E) atomicAdd(&deg[dst[e]], 1);
}

__global__ void k_scan1(const int* __restrict__ deg, int* __restrict__ excl,
                        int* __restrict__ bsum, int n) {
    __shared__ int sh[1024];
    int t = threadIdx.x;
    int i = blockIdx.x * 1024 + t;
    int v = (i < n) ? deg[i] : 0;
    sh[t] = v;
    __syncthreads();
    for (int off = 1; off < 1024; off <<= 1) {
        int add = (t >= off) ? sh[t - off] : 0;
        __syncthreads();
        sh[t] += add;
        __syncthreads();
    }
    if (i < n) excl[i] = sh[t] - v;
    if (t == 1023) bsum[blockIdx.x] = sh[t];
}

__global__ void k_scan2(int* __restrict__ bsum, int nb) {
    if (blockIdx.x == 0 && threadIdx.x == 0) {
        int run = 0;
        for (int b = 0; b < nb; ++b) { int v = bsum[b]; bsum[b] = run; run += v; }
    }
}

__global__ void k_scan3(int* __restrict__ row_start, const int* __restrict__ bsum, int n) {
    int i = blockIdx.x * blockDim.x + threadIdx.x;
    if (i < n) row_start[i] += bsum[i >> 10];
}

// fill: unique slot p per edge (per-dst counter); write 16-bit src via atomicOr
__global__ void k_fill(const int* __restrict__ src, const int* __restrict__ dst,
                       const int* __restrict__ row_start, int* __restrict__ fill,
                       unsigned* __restrict__ csr16w, int E) {
    int e = blockIdx.x * blockDim.x + threadIdx.x;
    if (e < E) {
        int d = dst[e];
        int p = row_start[d] + atomicAdd(&fill[d], 1);
        atomicOr(&csr16w[p >> 1], (unsigned)src[e] << ((p & 1) * 16));
    }
}

// ---------------- dtype converts ----------------

__global__ void k_cvt_x(const float* __restrict__ in, ushort* __restrict__ out, int n4) {
    int i = blockIdx.x * blockDim.x + threadIdx.x;
    if (i < n4) {
        float4 v = ((const float4*)in)[i];
        ushort4 o; o.x = f2bf(v.x); o.y = f2bf(v.y); o.z = f2bf(v.z); o.w = f2bf(v.w);
        ((ushort4*)out)[i] = o;
    }
}

struct CvtDesc {
    const float* s[6];
    ushort*      d[6];
    int K[6];
    int N[6];
};

__global__ void k_cvt_w6(CvtDesc c) {
    int wi = blockIdx.y;
    int t = blockIdx.x * blockDim.x + threadIdx.x;
    int K = c.K[wi], N = c.N[wi];
    if (t < K * N) {
        int k = t / N, n = t % N;
        c.d[wi][(size_t)n * K + k] = f2bf(c.s[wi][t]);
    }
}

// ---------------- mean aggregation + fused epilogue ----------------
// EPI: 0 = plain bf16 out; 1 = relu(agg+u+b) bf16 out; 2 = sigmoid(agg+u+b) f32 out

template <int F, int EPI>
__global__ __launch_bounds__(256)
void agg_bf(const ushort* __restrict__ in, const ushort* __restrict__ csr16,
            const int* __restrict__ row_start, const int* __restrict__ deg,
            const ushort* __restrict__ u, const float* __restrict__ bias,
            void* __restrict__ out, int nN) {
    int node = blockIdx.x * 4 + (threadIdx.x >> 6);
    if (node >= nN) return;
    int lane = threadIdx.x & 63;
    constexpr int EPL = F / 64;               // 1 or 2
    int start = row_start[node];
    int d = deg[node];
    float acc0 = 0.f, acc1 = 0.f;

    auto gat = [&](int j, int q) {
        int s = csr16[start + j + q];
        if constexpr (EPL == 2) {
            ushort2 uv = *(const ushort2*)(in + (size_t)s * F + lane * 2);
            acc0 += bf2f(uv.x); acc1 += bf2f(uv.y);
        } else {
            acc0 += bf2f(in[(size_t)s * F + lane]);
        }
    };

    int j = 0;
    for (; j + 8 <= d; j += 8) {
        gat(j,0); gat(j,1); gat(j,2); gat(j,3);
        gat(j,4); gat(j,5); gat(j,6); gat(j,7);
    }
    for (; j + 2 <= d; j += 2) { gat(j,0); gat(j,1); }
    for (; j < d; ++j) gat(j,0);

    float inv = 1.f / (float)(d > 0 ? d : 1);
    acc0 *= inv; acc1 *= inv;

    if constexpr (EPI == 0) {
        if constexpr (EPL == 2) {
            ushort2 o; o.x = f2bf(acc0); o.y = f2bf(acc1);
            *(ushort2*)((ushort*)out + (size_t)node * F + lane * 2) = o;
        } else {
            ((ushort*)out)[(size_t)node * F + lane] = f2bf(acc0);
        }
    } else if constexpr (EPL == 2) {
        ushort2 uv = *(const ushort2*)(u + (size_t)node * F + lane * 2);
        acc0 += bf2f(uv.x) + bias[lane * 2];
        acc1 += bf2f(uv.y) + bias[lane * 2 + 1];
        if constexpr (EPI == 1) {
            ushort2 o; o.x = f2bf(fmaxf(acc0, 0.f)); o.y = f2bf(fmaxf(acc1, 0.f));
            *(ushort2*)((ushort*)out + (size_t)node * F + lane * 2) = o;
        } else {
            float2 o; o.x = 1.f / (1.f + __expf(-acc0)); o.y = 1.f / (1.f + __expf(-acc1));
            *(float2*)((float*)out + (size_t)node * F + lane * 2) = o;
        }
    } else {
        float v = acc0 + bf2f(u[(size_t)node * F + lane]) + bias[lane];
        if constexpr (EPI == 1) {
            ((ushort*)out)[(size_t)node * F + lane] = f2bf(fmaxf(v, 0.f));
        } else {
            ((float*)out)[(size_t)node * F + lane] = 1.f / (1.f + __expf(-v));
        }
    }
}

// ---------------- bf16 MFMA GEMM (BK=64 loop), split-output epilogue --------
// C[M,N] = act( A1@B1^T (+ A2@B2^T) (+ bias) ); col < nsplit -> C1, else C2.
// A: [M][K] bf16. B: [N][K] bf16 (pre-transposed). LDS XOR-swizzled.

template <int BM, int BN, int WM, int WN, int ACT>
__global__ __launch_bounds__(WM * WN * 64)
void mgemm(const ushort* __restrict__ A1, const ushort* __restrict__ B1, int K1,
           const ushort* __restrict__ A2, const ushort* __restrict__ B2, int K2,
           const float* __restrict__ bias,
           ushort* __restrict__ C1, int ld1,
           ushort* __restrict__ C2, int ld2, int nsplit,
           int M, int N) {
    constexpr int NT = WM * WN * 64;
    constexpr int MF = BM / (WM * 16);
    constexpr int NF = BN / (WN * 16);
    __shared__ char lds[(BM + BN) * 128];     // rows x 64 bf16
    char* As = lds;
    char* Bs = lds + BM * 128;

    const int tid  = threadIdx.x;
    const int lane = tid & 63;
    const int wid  = tid >> 6;
    const int wm   = wid % WM, wn = wid / WM;
    const int bm   = blockIdx.x * BM;
    const int bn   = blockIdx.y * BN;
    const int l15  = lane & 15;
    const int lhi  = lane >> 4;

    f32x4 acc[MF][NF] = {};

    for (int pass = 0; pass < 2; ++pass) {
        const ushort* A = pass ? A2 : A1;
        const ushort* B = pass ? B2 : B1;
        const int K = pass ? K2 : K1;
        if (A == nullptr) continue;
        for (int k0 = 0; k0 < K; k0 += 64) {
            #pragma unroll
            for (int it = 0; it < BM * 8 / NT; ++it) {       // stage A
                int flat = it * NT + tid;
                int row = flat >> 3;
                int cb = (flat & 7) * 16;
                frag v = {};
                int gr = bm + row;
                if (gr < M) v = *(const frag*)(A + (size_t)gr * K + k0 + (flat & 7) * 8);
                *(frag*)(As + row * 128 + (cb ^ ((row & 7) << 4))) = v;
            }
            #pragma unroll
            for (int it = 0; it < BN * 8 / NT; ++it) {       // stage B
                int flat = it * NT + tid;
                int row = flat >> 3;
                int cb = (flat & 7) * 16;
                frag v = *(const frag*)(B + (size_t)(bn + row) * K + k0 + (flat & 7) * 8);
                *(frag*)(Bs + row * 128 + (cb ^ ((row & 7) << 4))) = v;
            }
            __syncthreads();
            #pragma unroll
            for (int ks = 0; ks < 2; ++ks) {
                const int kb = ks * 64 + lhi * 16;
                frag a[MF], b[NF];
                #pragma unroll
                for (int mf = 0; mf < MF; ++mf) {
                    int row = wm * MF * 16 + mf * 16 + l15;
                    a[mf] = *(const frag*)(As + row * 128 + (kb ^ ((row & 7) << 4)));
                }
                #pragma unroll
                for (int nf = 0; nf < NF; ++nf) {
                    int row = wn * NF * 16 + nf * 16 + l15;
                    b[nf] = *(const frag*)(Bs + row * 128 + (kb ^ ((row & 7) << 4)));
                }
                #pragma unroll
                for (int mf = 0; mf < MF; ++mf)
                    #pragma unroll
                    for (int nf = 0; nf < NF; ++nf)
                        acc[mf][nf] = __builtin_amdgcn_mfma_f32_16x16x32_bf16(
                            a[mf], b[nf], acc[mf][nf], 0, 0, 0);
            }
            __syncthreads();
        }
    }

    #pragma unroll
    for (int mf = 0; mf < MF; ++mf) {
        #pragma unroll
        for (int r = 0; r < 4; ++r) {
            int gm = bm + wm * MF * 16 + mf * 16 + lhi * 4 + r;
            if (gm >= M) continue;
            #pragma unroll
            for (int nf = 0; nf < NF; ++nf) {
                int gn = bn + wn * NF * 16 + nf * 16 + l15;
                float v = acc[mf][nf][r];
                if (bias) v += bias[gn];
                if (ACT == 1) v = fmaxf(v, 0.f);
                ushort o = f2bf(v);
                if (gn < nsplit) C1[(size_t)gm * ld1 + gn] = o;
                else             C2[(size_t)gm * ld2 + (gn - nsplit)] = o;
            }
        }
    }
}

// ---------------------------------------------------------------------------

extern "C" void kernel_launch(void* const* d_in, const int* in_sizes, int n_in,
                              void* d_out, int out_size, void* d_ws, size_t ws_size,
                              hipStream_t stream) {
    const float* x   = (const float*)d_in[0];
    const int*   ei  = (const int*)d_in[1];
    const float* Wl1 = (const float*)d_in[2];
    const float* Wr1 = (const float*)d_in[3];
    const float* b1  = (const float*)d_in[4];
    const float* Wl2 = (const float*)d_in[5];
    const float* Wr2 = (const float*)d_in[6];
    const float* b2  = (const float*)d_in[7];
    const float* Wl3 = (const float*)d_in[8];
    const float* Wr3 = (const float*)d_in[9];
    const float* b3  = (const float*)d_in[10];

    const int M = in_sizes[0] / 128;   // 50000
    const int E = in_sizes[1] / 2;     // 800000
    const int* src = ei;
    const int* dst = ei + E;

    char* w = (char*)d_ws;
    auto alloc = [&](size_t bytes) -> void* {
        void* p = (void*)w;
        w += (bytes + 255) & ~(size_t)255;
        return p;
    };
    // deg, fill, csr16 contiguous -> single memset
    int* deg       = (int*)alloc((size_t)M * 4);
    int* fill      = (int*)alloc((size_t)M * 4);
    unsigned* csr16w = (unsigned*)alloc((size_t)E * 2);
    int* row_start = (int*)alloc((size_t)M * 4);
    int* bsum      = (int*)alloc(256 * 4);
    ushort* Wl1t   = (ushort*)alloc(256 * 128 * 2);       // [256][128]
    ushort* Wr1t   = (ushort*)alloc(256 * 128 * 2);       // [256][128]
    ushort* Wcat2T = (ushort*)alloc(256 * 256 * 2);       // [256][256]: Wl2|Wr2 rows
    ushort* Wcat3T = (ushort*)alloc(128 * 128 * 2);       // [128][128]: Wl3|Wr3 rows
    ushort* bufA = (ushort*)alloc((size_t)M * 128 * 2);   // x_bf -> t2 -> t3
    ushort* bufB = (ushort*)alloc((size_t)M * 128 * 2);   // aggx -> h2
    ushort* bufH = (ushort*)alloc((size_t)M * 256 * 2);   // h1
    ushort* bufC = (ushort*)alloc((size_t)M * 128 * 2);   // u2 -> u3
    (void)ws_size; (void)n_in; (void)out_size;

    const ushort* csr16 = (const ushort*)csr16w;
    ushort* x_bf = bufA; ushort* t2 = bufA; ushort* t3 = bufA;
    ushort* aggx = bufB; ushort* h2 = bufB;
    ushort* h1 = bufH;
    ushort* u2 = bufC;   ushort* u3 = bufC;

    // one memset covers deg + fill + csr16 (contiguous, pads included)
    hipMemsetAsync(deg, 0, (size_t)((char*)csr16w - (char*)deg) + (size_t)E * 2, stream);

    // CSR build
    k_degree<<<(E + 255) / 256, 256, 0, stream>>>(dst, deg, E);
    const int nb = (M + 1023) / 1024;
    k_scan1<<<nb, 1024, 0, stream>>>(deg, row_start, bsum, M);
    k_scan2<<<1, 64, 0, stream>>>(bsum, nb);
    k_scan3<<<(M + 255) / 256, 256, 0, stream>>>(row_start, bsum, M);
    k_fill<<<(E + 255) / 256, 256, 0, stream>>>(src, dst, row_start, fill, csr16w, E);

    // converts
    k_cvt_x<<<(M * 128 / 4 + 255) / 256, 256, 0, stream>>>(x, x_bf, M * 128 / 4);
    CvtDesc cd;
    cd.s[0] = Wl1; cd.d[0] = Wl1t;             cd.K[0] = 128; cd.N[0] = 256;
    cd.s[1] = Wr1; cd.d[1] = Wr1t;             cd.K[1] = 128; cd.N[1] = 256;
    cd.s[2] = Wl2; cd.d[2] = Wcat2T;           cd.K[2] = 256; cd.N[2] = 128;
    cd.s[3] = Wr2; cd.d[3] = Wcat2T + 128*256; cd.K[3] = 256; cd.N[3] = 128;
    cd.s[4] = Wl3; cd.d[4] = Wcat3T;           cd.K[4] = 128; cd.N[4] = 64;
    cd.s[5] = Wr3; cd.d[5] = Wcat3T + 64*128;  cd.K[5] = 128; cd.N[5] = 64;
    k_cvt_w6<<<dim3(128, 6), 256, 0, stream>>>(cd);

    const int gm64 = (M + 63) / 64;           // 782
    const int gagg = (M + 3) / 4;             // 12500

    // ---- layer 1: aggx = agg(x); h1 = relu(aggx@Wl1 + x@Wr1 + b1)
    agg_bf<128, 0><<<gagg, 256, 0, stream>>>(x_bf, csr16, row_start, deg,
                                             nullptr, nullptr, aggx, M);
    mgemm<64, 64, 2, 2, 1><<<dim3(gm64, 4), 256, 0, stream>>>(
        aggx, Wl1t, 128, x_bf, Wr1t, 128, b1,
        h1, 256, nullptr, 0, 256, M, 256);

    // ---- layer 2: [t2|u2] = h1@Wcat2; h2 = relu(agg(t2) + u2 + b2)
    mgemm<64, 64, 2, 2, 0><<<dim3(gm64, 4), 256, 0, stream>>>(
        h1, Wcat2T, 256, nullptr, nullptr, 0, nullptr,
        t2, 128, u2, 128, 128, M, 256);
    agg_bf<128, 1><<<gagg, 256, 0, stream>>>(t2, csr16, row_start, deg,
                                             u2, b2, h2, M);

    // ---- layer 3: [t3|u3] = h2@Wcat3; out = sigmoid(agg(t3) + u3 + b3)
    mgemm<64, 64, 2, 2, 0><<<dim3(gm64, 2), 256, 0, stream>>>(
        h2, Wcat3T, 128, nullptr, nullptr, 0, nullptr,
        t3, 64, u3, 64, 64, M, 128);
    agg_bf<64, 2><<<gagg, 256, 0, stream>>>(t3, csr16, row_start, deg,
                                            u3, b3, (float*)d_out, M);
}

// Round 10
// 219.578 us; speedup vs baseline: 1.3593x; 1.3076x over previous
//
#include <hip/hip_runtime.h>
#include <cstddef>

// ---------------------------------------------------------------------------
// SAGEBlock: 3-layer GraphSAGE (mean aggr), N=50000, E=800000.
//   h1 = relu(agg(x)@Wl1 + x@Wr1 + b1)              128 -> 256
//   h2 = relu(agg(h1@Wl2) + h1@Wr2 + b2)            256 -> 128
//   out= sigmoid(agg(h2@Wl3) + h2@Wr3 + b3)         128 -> 64
// R10: CSR build as LDS-binned counting sort by dst-partition (P=512-node
//     partitions). Random 4B scatters paid 64B/line (51MB writeback, R6/R8);
//     per-WG LDS binning + run-claiming writes ~170B contiguous runs (~1.2x),
//     and the final per-partition csr scatter stays inside one XCD's L2.
//     Replaces k_degree + 3 scans + k_fill + 3.2MB memset entirely.
// ---------------------------------------------------------------------------

using frag  = __attribute__((ext_vector_type(8))) short;   // 8 bf16
using f32x4 = __attribute__((ext_vector_type(4))) float;

constexpr int PBITS = 9;                 // 512 nodes per partition
constexpr int PSZ   = 1 << PBITS;
constexpr int PMAX  = 128;               // max partitions (M <= 65536)

__device__ __forceinline__ ushort f2bf(float f) {
    union { float f; unsigned u; } v; v.f = f;
    unsigned r = v.u + 0x7FFF + ((v.u >> 16) & 1);   // RNE
    return (ushort)(r >> 16);
}
__device__ __forceinline__ float bf2f(ushort u) {
    union { unsigned u; float f; } v; v.u = ((unsigned)u) << 16;
    return v.f;
}

// ---------------- CSR build: counting sort by partition ----------------

// per-WG LDS histogram, one global atomic per (WG, partition)
__global__ __launch_bounds__(256)
void k_pcount(const int* __restrict__ dst, int* __restrict__ pcount, int E, int P) {
    __shared__ int h[PMAX];
    int t = threadIdx.x;
    if (t < P) h[t] = 0;
    __syncthreads();
    int base = blockIdx.x * 4096;
    int n = min(4096, E - base);
    for (int i = t; i < n; i += 256)
        atomicAdd(&h[dst[base + i] >> PBITS], 1);
    __syncthreads();
    if (t < P && h[t]) atomicAdd(&pcount[t], h[t]);
}

__global__ void k_pscan(const int* __restrict__ pcount, int* __restrict__ pbase,
                        int* __restrict__ pcursor, int P) {
    if (threadIdx.x == 0) {
        int run = 0;
        for (int p = 0; p < P; ++p) { pbase[p] = run; pcursor[p] = run; run += pcount[p]; }
        pbase[P] = run;
    }
}

// per-WG: LDS provisional ranks, claim per-partition runs, write packed
// (localnode<<16 | src) into contiguous runs of the partition windows.
__global__ __launch_bounds__(256)
void k_scatter(const int* __restrict__ src, const int* __restrict__ dst,
               int* __restrict__ pcursor, unsigned* __restrict__ pairs, int E, int P) {
    __shared__ int h[PMAX];
    __shared__ int off[PMAX];
    int t = threadIdx.x;
    if (t < P) h[t] = 0;
    __syncthreads();
    int base = blockIdx.x * 4096;
    int pp[16]; int pr[16]; unsigned pk[16];
    #pragma unroll
    for (int ii = 0; ii < 16; ++ii) {          // static index -> stays in VGPRs
        int idx = base + ii * 256 + t;
        bool v = idx < E;
        int d = v ? dst[idx] : 0;
        int p = d >> PBITS;
        pp[ii] = v ? p : -1;
        pr[ii] = v ? atomicAdd(&h[p], 1) : 0;
        pk[ii] = v ? ((unsigned)src[idx] | ((unsigned)(d & (PSZ - 1)) << 16)) : 0u;
    }
    __syncthreads();
    if (t < P && h[t]) off[t] = atomicAdd(&pcursor[t], h[t]);
    __syncthreads();
    #pragma unroll
    for (int ii = 0; ii < 16; ++ii)
        if (pp[ii] >= 0) pairs[off[pp[ii]] + pr[ii]] = pk[ii];
}

// one WG per partition: LDS degree histogram + prefix scan -> deg/row_start
// (coalesced), then csr16 scatter confined to this partition's window.
__global__ __launch_bounds__(256)
void k_build(const unsigned* __restrict__ pairs, const int* __restrict__ pbase,
             int* __restrict__ deg, int* __restrict__ row_start,
             ushort* __restrict__ csr16, int M) {
    __shared__ int cnt[PSZ];
    __shared__ int ls[PSZ];
    __shared__ int fil[PSZ];
    __shared__ int ws[256];
    int pid = blockIdx.x;
    int t = threadIdx.x;
    int n0 = pid << PBITS;
    int L = min(PSZ, M - n0);
    int wb = pbase[pid], we = pbase[pid + 1];
    int ne = we - wb;
    for (int j = t; j < PSZ; j += 256) { cnt[j] = 0; fil[j] = 0; }
    __syncthreads();
    for (int i = t; i < ne; i += 256)
        atomicAdd(&cnt[pairs[wb + i] >> 16], 1);
    __syncthreads();
    int a = cnt[2 * t], b = cnt[2 * t + 1];
    ws[t] = a + b;
    __syncthreads();
    for (int o = 1; o < 256; o <<= 1) {
        int v = (t >= o) ? ws[t - o] : 0;
        __syncthreads();
        ws[t] += v;
        __syncthreads();
    }
    int excl = (t > 0) ? ws[t - 1] : 0;
    ls[2 * t] = excl; ls[2 * t + 1] = excl + a;
    __syncthreads();
    for (int j = t; j < L; j += 256) {
        deg[n0 + j] = cnt[j];
        row_start[n0 + j] = wb + ls[j];
    }
    for (int i = t; i < ne; i += 256) {
        unsigned pk = pairs[wb + i];
        int ln = pk >> 16;
        int pos = wb + ls[ln] + atomicAdd(&fil[ln], 1);
        csr16[pos] = (ushort)(pk & 0xFFFFu);
    }
}

// ---------------- dtype converts ----------------

__global__ void k_cvt_x(const float* __restrict__ in, ushort* __restrict__ out, int n4) {
    int i = blockIdx.x * blockDim.x + threadIdx.x;
    if (i < n4) {
        float4 v = ((const float4*)in)[i];
        ushort4 o; o.x = f2bf(v.x); o.y = f2bf(v.y); o.z = f2bf(v.z); o.w = f2bf(v.w);
        ((ushort4*)out)[i] = o;
    }
}

struct CvtDesc {
    const float* s[6];
    ushort*      d[6];
    int K[6];
    int N[6];
};

__global__ void k_cvt_w6(CvtDesc c) {
    int wi = blockIdx.y;
    int t = blockIdx.x * blockDim.x + threadIdx.x;
    int K = c.K[wi], N = c.N[wi];
    if (t < K * N) {
        int k = t / N, n = t % N;
        c.d[wi][(size_t)n * K + k] = f2bf(c.s[wi][t]);
    }
}

// ---------------- mean aggregation + fused epilogue ----------------
// EPI: 0 = plain bf16 out; 1 = relu(agg+u+b) bf16 out; 2 = sigmoid(agg+u+b) f32 out

template <int F, int EPI>
__global__ __launch_bounds__(256)
void agg_bf(const ushort* __restrict__ in, const ushort* __restrict__ csr16,
            const int* __restrict__ row_start, const int* __restrict__ deg,
            const ushort* __restrict__ u, const float* __restrict__ bias,
            void* __restrict__ out, int nN) {
    int node = blockIdx.x * 4 + (threadIdx.x >> 6);
    if (node >= nN) return;
    int lane = threadIdx.x & 63;
    constexpr int EPL = F / 64;               // 1 or 2
    int start = row_start[node];
    int d = deg[node];
    float acc0 = 0.f, acc1 = 0.f;

    auto gat = [&](int j, int q) {
        int s = csr16[start + j + q];
        if constexpr (EPL == 2) {
            ushort2 uv = *(const ushort2*)(in + (size_t)s * F + lane * 2);
            acc0 += bf2f(uv.x); acc1 += bf2f(uv.y);
        } else {
            acc0 += bf2f(in[(size_t)s * F + lane]);
        }
    };

    int j = 0;
    for (; j + 8 <= d; j += 8) {
        gat(j,0); gat(j,1); gat(j,2); gat(j,3);
        gat(j,4); gat(j,5); gat(j,6); gat(j,7);
    }
    for (; j + 2 <= d; j += 2) { gat(j,0); gat(j,1); }
    for (; j < d; ++j) gat(j,0);

    float inv = 1.f / (float)(d > 0 ? d : 1);
    acc0 *= inv; acc1 *= inv;

    if constexpr (EPI == 0) {
        if constexpr (EPL == 2) {
            ushort2 o; o.x = f2bf(acc0); o.y = f2bf(acc1);
            *(ushort2*)((ushort*)out + (size_t)node * F + lane * 2) = o;
        } else {
            ((ushort*)out)[(size_t)node * F + lane] = f2bf(acc0);
        }
    } else if constexpr (EPL == 2) {
        ushort2 uv = *(const ushort2*)(u + (size_t)node * F + lane * 2);
        acc0 += bf2f(uv.x) + bias[lane * 2];
        acc1 += bf2f(uv.y) + bias[lane * 2 + 1];
        if constexpr (EPI == 1) {
            ushort2 o; o.x = f2bf(fmaxf(acc0, 0.f)); o.y = f2bf(fmaxf(acc1, 0.f));
            *(ushort2*)((ushort*)out + (size_t)node * F + lane * 2) = o;
        } else {
            float2 o; o.x = 1.f / (1.f + __expf(-acc0)); o.y = 1.f / (1.f + __expf(-acc1));
            *(float2*)((float*)out + (size_t)node * F + lane * 2) = o;
        }
    } else {
        float v = acc0 + bf2f(u[(size_t)node * F + lane]) + bias[lane];
        if constexpr (EPI == 1) {
            ((ushort*)out)[(size_t)node * F + lane] = f2bf(fmaxf(v, 0.f));
        } else {
            ((float*)out)[(size_t)node * F + lane] = 1.f / (1.f + __expf(-v));
        }
    }
}

// ---------------- bf16 MFMA GEMM (BK=64 loop), split-output epilogue --------
// C[M,N] = act( A1@B1^T (+ A2@B2^T) (+ bias) ); col < nsplit -> C1, else C2.
// A: [M][K] bf16. B: [N][K] bf16 (pre-transposed). LDS XOR-swizzled.

template <int BM, int BN, int WM, int WN, int ACT>
__global__ __launch_bounds__(WM * WN * 64)
void mgemm(const ushort* __restrict__ A1, const ushort* __restrict__ B1, int K1,
           const ushort* __restrict__ A2, const ushort* __restrict__ B2, int K2,
           const float* __restrict__ bias,
           ushort* __restrict__ C1, int ld1,
           ushort* __restrict__ C2, int ld2, int nsplit,
           int M, int N) {
    constexpr int NT = WM * WN * 64;
    constexpr int MF = BM / (WM * 16);
    constexpr int NF = BN / (WN * 16);
    __shared__ char lds[(BM + BN) * 128];     // rows x 64 bf16
    char* As = lds;
    char* Bs = lds + BM * 128;

    const int tid  = threadIdx.x;
    const int lane = tid & 63;
    const int wid  = tid >> 6;
    const int wm   = wid % WM, wn = wid / WM;
    const int bm   = blockIdx.x * BM;
    const int bn   = blockIdx.y * BN;
    const int l15  = lane & 15;
    const int lhi  = lane >> 4;

    f32x4 acc[MF][NF] = {};

    for (int pass = 0; pass < 2; ++pass) {
        const ushort* A = pass ? A2 : A1;
        const ushort* B = pass ? B2 : B1;
        const int K = pass ? K2 : K1;
        if (A == nullptr) continue;
        for (int k0 = 0; k0 < K; k0 += 64) {
            #pragma unroll
            for (int it = 0; it < BM * 8 / NT; ++it) {       // stage A
                int flat = it * NT + tid;
                int row = flat >> 3;
                int cb = (flat & 7) * 16;
                frag v = {};
                int gr = bm + row;
                if (gr < M) v = *(const frag*)(A + (size_t)gr * K + k0 + (flat & 7) * 8);
                *(frag*)(As + row * 128 + (cb ^ ((row & 7) << 4))) = v;
            }
            #pragma unroll
            for (int it = 0; it < BN * 8 / NT; ++it) {       // stage B
                int flat = it * NT + tid;
                int row = flat >> 3;
                int cb = (flat & 7) * 16;
                frag v = *(const frag*)(B + (size_t)(bn + row) * K + k0 + (flat & 7) * 8);
                *(frag*)(Bs + row * 128 + (cb ^ ((row & 7) << 4))) = v;
            }
            __syncthreads();
            #pragma unroll
            for (int ks = 0; ks < 2; ++ks) {
                const int kb = ks * 64 + lhi * 16;
                frag a[MF], b[NF];
                #pragma unroll
                for (int mf = 0; mf < MF; ++mf) {
                    int row = wm * MF * 16 + mf * 16 + l15;
                    a[mf] = *(const frag*)(As + row * 128 + (kb ^ ((row & 7) << 4)));
                }
                #pragma unroll
                for (int nf = 0; nf < NF; ++nf) {
                    int row = wn * NF * 16 + nf * 16 + l15;
                    b[nf] = *(const frag*)(Bs + row * 128 + (kb ^ ((row & 7) << 4)));
                }
                #pragma unroll
                for (int mf = 0; mf < MF; ++mf)
                    #pragma unroll
                    for (int nf = 0; nf < NF; ++nf)
                        acc[mf][nf] = __builtin_amdgcn_mfma_f32_16x16x32_bf16(
                            a[mf], b[nf], acc[mf][nf], 0, 0, 0);
            }
            __syncthreads();
        }
    }

    #pragma unroll
    for (int mf = 0; mf < MF; ++mf) {
        #pragma unroll
        for (int r = 0; r < 4; ++r) {
            int gm = bm + wm * MF * 16 + mf * 16 + lhi * 4 + r;
            if (gm >= M) continue;
            #pragma unroll
            for (int nf = 0; nf < NF; ++nf) {
                int gn = bn + wn * NF * 16 + nf * 16 + l15;
                float v = acc[mf][nf][r];
                if (bias) v += bias[gn];
                if (ACT == 1) v = fmaxf(v, 0.f);
                ushort o = f2bf(v);
                if (gn < nsplit) C1[(size_t)gm * ld1 + gn] = o;
                else             C2[(size_t)gm * ld2 + (gn - nsplit)] = o;
            }
        }
    }
}

// ---------------------------------------------------------------------------

extern "C" void kernel_launch(void* const* d_in, const int* in_sizes, int n_in,
                              void* d_out, int out_size, void* d_ws, size_t ws_size,
                              hipStream_t stream) {
    const float* x   = (const float*)d_in[0];
    const int*   ei  = (const int*)d_in[1];
    const float* Wl1 = (const float*)d_in[2];
    const float* Wr1 = (const float*)d_in[3];
    const float* b1  = (const float*)d_in[4];
    const float* Wl2 = (const float*)d_in[5];
    const float* Wr2 = (const float*)d_in[6];
    const float* b2  = (const float*)d_in[7];
    const float* Wl3 = (const float*)d_in[8];
    const float* Wr3 = (const float*)d_in[9];
    const float* b3  = (const float*)d_in[10];

    const int M = in_sizes[0] / 128;   // 50000
    const int E = in_sizes[1] / 2;     // 800000
    const int P = (M + PSZ - 1) / PSZ; // 98 partitions
    const int* src = ei;
    const int* dst = ei + E;

    char* w = (char*)d_ws;
    auto alloc = [&](size_t bytes) -> void* {
        void* p = (void*)w;
        w += (bytes + 255) & ~(size_t)255;
        return p;
    };
    int* pcount    = (int*)alloc((size_t)PMAX * 4);
    int* pbase     = (int*)alloc((size_t)(PMAX + 1) * 4);
    int* pcursor   = (int*)alloc((size_t)PMAX * 4);
    unsigned* pairs = (unsigned*)alloc((size_t)E * 4);
    ushort* csr16  = (ushort*)alloc((size_t)E * 2);
    int* deg       = (int*)alloc((size_t)M * 4);
    int* row_start = (int*)alloc((size_t)M * 4);
    ushort* Wl1t   = (ushort*)alloc(256 * 128 * 2);       // [256][128]
    ushort* Wr1t   = (ushort*)alloc(256 * 128 * 2);       // [256][128]
    ushort* Wcat2T = (ushort*)alloc(256 * 256 * 2);       // [256][256]: Wl2|Wr2 rows
    ushort* Wcat3T = (ushort*)alloc(128 * 128 * 2);       // [128][128]: Wl3|Wr3 rows
    ushort* bufA = (ushort*)alloc((size_t)M * 128 * 2);   // x_bf -> t2 -> t3
    ushort* bufB = (ushort*)alloc((size_t)M * 128 * 2);   // aggx -> h2
    ushort* bufH = (ushort*)alloc((size_t)M * 256 * 2);   // h1
    ushort* bufC = (ushort*)alloc((size_t)M * 128 * 2);   // u2 -> u3
    (void)ws_size; (void)n_in; (void)out_size;

    ushort* x_bf = bufA; ushort* t2 = bufA; ushort* t3 = bufA;
    ushort* aggx = bufB; ushort* h2 = bufB;
    ushort* h1 = bufH;
    ushort* u2 = bufC;   ushort* u3 = bufC;

    // CSR build: only pcount needs zeroing (<=512B)
    hipMemsetAsync(pcount, 0, (size_t)PMAX * 4, stream);
    const int nchunk = (E + 4095) / 4096;     // 196
    k_pcount<<<nchunk, 256, 0, stream>>>(dst, pcount, E, P);
    k_pscan<<<1, 64, 0, stream>>>(pcount, pbase, pcursor, P);
    k_scatter<<<nchunk, 256, 0, stream>>>(src, dst, pcursor, pairs, E, P);
    k_build<<<P, 256, 0, stream>>>(pairs, pbase, deg, row_start, csr16, M);

    // converts
    k_cvt_x<<<(M * 128 / 4 + 255) / 256, 256, 0, stream>>>(x, x_bf, M * 128 / 4);
    CvtDesc cd;
    cd.s[0] = Wl1; cd.d[0] = Wl1t;             cd.K[0] = 128; cd.N[0] = 256;
    cd.s[1] = Wr1; cd.d[1] = Wr1t;             cd.K[1] = 128; cd.N[1] = 256;
    cd.s[2] = Wl2; cd.d[2] = Wcat2T;           cd.K[2] = 256; cd.N[2] = 128;
    cd.s[3] = Wr2; cd.d[3] = Wcat2T + 128*256; cd.K[3] = 256; cd.N[3] = 128;
    cd.s[4] = Wl3; cd.d[4] = Wcat3T;           cd.K[4] = 128; cd.N[4] = 64;
    cd.s[5] = Wr3; cd.d[5] = Wcat3T + 64*128;  cd.K[5] = 128; cd.N[5] = 64;
    k_cvt_w6<<<dim3(128, 6), 256, 0, stream>>>(cd);

    const int gm64 = (M + 63) / 64;           // 782
    const int gagg = (M + 3) / 4;             // 12500

    // ---- layer 1: aggx = agg(x); h1 = relu(aggx@Wl1 + x@Wr1 + b1)
    agg_bf<128, 0><<<gagg, 256, 0, stream>>>(x_bf, csr16, row_start, deg,
                                             nullptr, nullptr, aggx, M);
    mgemm<64, 64, 2, 2, 1><<<dim3(gm64, 4), 256, 0, stream>>>(
        aggx, Wl1t, 128, x_bf, Wr1t, 128, b1,
        h1, 256, nullptr, 0, 256, M, 256);

    // ---- layer 2: [t2|u2] = h1@Wcat2; h2 = relu(agg(t2) + u2 + b2)
    mgemm<64, 64, 2, 2, 0><<<dim3(gm64, 4), 256, 0, stream>>>(
        h1, Wcat2T, 256, nullptr, nullptr, 0, nullptr,
        t2, 128, u2, 128, 128, M, 256);
    agg_bf<128, 1><<<gagg, 256, 0, stream>>>(t2, csr16, row_start, deg,
                                             u2, b2, h2, M);

    // ---- layer 3: [t3|u3] = h2@Wcat3; out = sigmoid(agg(t3) + u3 + b3)
    mgemm<64, 64, 2, 2, 0><<<dim3(gm64, 2), 256, 0, stream>>>(
        h2, Wcat3T, 128, nullptr, nullptr, 0, nullptr,
        t3, 64, u3, 64, 64, M, 128);
    agg_bf<64, 2><<<gagg, 256, 0, stream>>>(t3, csr16, row_start, deg,
                                            u3, b3, (float*)d_out, M);
}

// Round 11
// 217.334 us; speedup vs baseline: 1.3733x; 1.0103x over previous
//
#include <hip/hip_runtime.h>
#include <cstddef>

// ---------------------------------------------------------------------------
// SAGEBlock: 3-layer GraphSAGE (mean aggr), N=50000, E=800000.
//   h1 = relu(agg(x)@Wl1 + x@Wr1 + b1)              128 -> 256
//   h2 = relu(agg(h1@Wl2) + h1@Wr2 + b2)            256 -> 128
//   out= sigmoid(agg(h2@Wl3) + h2@Wr3 + b3)         128 -> 64
// R11: agg with F/4 lanes per node (ushort4 8B loads, 2-4 nodes/wave;
//     halves/quarters wave count in the LLC-gather-bound phase) and
//     mgemm BM=128 (16 MFMA per stage, same 2-barrier BK=64 structure).
//     CSR build: R10's LDS-binned counting sort (proven).
// ---------------------------------------------------------------------------

using frag  = __attribute__((ext_vector_type(8))) short;   // 8 bf16
using f32x4 = __attribute__((ext_vector_type(4))) float;

constexpr int PBITS = 9;                 // 512 nodes per partition
constexpr int PSZ   = 1 << PBITS;
constexpr int PMAX  = 128;               // max partitions (M <= 65536)

__device__ __forceinline__ ushort f2bf(float f) {
    union { float f; unsigned u; } v; v.f = f;
    unsigned r = v.u + 0x7FFF + ((v.u >> 16) & 1);   // RNE
    return (ushort)(r >> 16);
}
__device__ __forceinline__ float bf2f(ushort u) {
    union { unsigned u; float f; } v; v.u = ((unsigned)u) << 16;
    return v.f;
}

// ---------------- CSR build: counting sort by partition ----------------

__global__ __launch_bounds__(256)
void k_pcount(const int* __restrict__ dst, int* __restrict__ pcount, int E, int P) {
    __shared__ int h[PMAX];
    int t = threadIdx.x;
    if (t < P) h[t] = 0;
    __syncthreads();
    int base = blockIdx.x * 4096;
    int n = min(4096, E - base);
    for (int i = t; i < n; i += 256)
        atomicAdd(&h[dst[base + i] >> PBITS], 1);
    __syncthreads();
    if (t < P && h[t]) atomicAdd(&pcount[t], h[t]);
}

__global__ void k_pscan(const int* __restrict__ pcount, int* __restrict__ pbase,
                        int* __restrict__ pcursor, int P) {
    if (threadIdx.x == 0) {
        int run = 0;
        for (int p = 0; p < P; ++p) { pbase[p] = run; pcursor[p] = run; run += pcount[p]; }
        pbase[P] = run;
    }
}

__global__ __launch_bounds__(256)
void k_scatter(const int* __restrict__ src, const int* __restrict__ dst,
               int* __restrict__ pcursor, unsigned* __restrict__ pairs, int E, int P) {
    __shared__ int h[PMAX];
    __shared__ int off[PMAX];
    int t = threadIdx.x;
    if (t < P) h[t] = 0;
    __syncthreads();
    int base = blockIdx.x * 4096;
    int pp[16]; int pr[16]; unsigned pk[16];
    #pragma unroll
    for (int ii = 0; ii < 16; ++ii) {          // static index -> stays in VGPRs
        int idx = base + ii * 256 + t;
        bool v = idx < E;
        int d = v ? dst[idx] : 0;
        int p = d >> PBITS;
        pp[ii] = v ? p : -1;
        pr[ii] = v ? atomicAdd(&h[p], 1) : 0;
        pk[ii] = v ? ((unsigned)src[idx] | ((unsigned)(d & (PSZ - 1)) << 16)) : 0u;
    }
    __syncthreads();
    if (t < P && h[t]) off[t] = atomicAdd(&pcursor[t], h[t]);
    __syncthreads();
    #pragma unroll
    for (int ii = 0; ii < 16; ++ii)
        if (pp[ii] >= 0) pairs[off[pp[ii]] + pr[ii]] = pk[ii];
}

__global__ __launch_bounds__(256)
void k_build(const unsigned* __restrict__ pairs, const int* __restrict__ pbase,
             int* __restrict__ deg, int* __restrict__ row_start,
             ushort* __restrict__ csr16, int M) {
    __shared__ int cnt[PSZ];
    __shared__ int ls[PSZ];
    __shared__ int fil[PSZ];
    __shared__ int ws[256];
    int pid = blockIdx.x;
    int t = threadIdx.x;
    int n0 = pid << PBITS;
    int L = min(PSZ, M - n0);
    int wb = pbase[pid], we = pbase[pid + 1];
    int ne = we - wb;
    for (int j = t; j < PSZ; j += 256) { cnt[j] = 0; fil[j] = 0; }
    __syncthreads();
    for (int i = t; i < ne; i += 256)
        atomicAdd(&cnt[pairs[wb + i] >> 16], 1);
    __syncthreads();
    int a = cnt[2 * t], b = cnt[2 * t + 1];
    ws[t] = a + b;
    __syncthreads();
    for (int o = 1; o < 256; o <<= 1) {
        int v = (t >= o) ? ws[t - o] : 0;
        __syncthreads();
        ws[t] += v;
        __syncthreads();
    }
    int excl = (t > 0) ? ws[t - 1] : 0;
    ls[2 * t] = excl; ls[2 * t + 1] = excl + a;
    __syncthreads();
    for (int j = t; j < L; j += 256) {
        deg[n0 + j] = cnt[j];
        row_start[n0 + j] = wb + ls[j];
    }
    for (int i = t; i < ne; i += 256) {
        unsigned pk = pairs[wb + i];
        int ln = pk >> 16;
        int pos = wb + ls[ln] + atomicAdd(&fil[ln], 1);
        csr16[pos] = (ushort)(pk & 0xFFFFu);
    }
}

// ---------------- dtype converts ----------------

__global__ void k_cvt_x(const float* __restrict__ in, ushort* __restrict__ out, int n4) {
    int i = blockIdx.x * blockDim.x + threadIdx.x;
    if (i < n4) {
        float4 v = ((const float4*)in)[i];
        ushort4 o; o.x = f2bf(v.x); o.y = f2bf(v.y); o.z = f2bf(v.z); o.w = f2bf(v.w);
        ((ushort4*)out)[i] = o;
    }
}

struct CvtDesc {
    const float* s[6];
    ushort*      d[6];
    int K[6];
    int N[6];
};

__global__ void k_cvt_w6(CvtDesc c) {
    int wi = blockIdx.y;
    int t = blockIdx.x * blockDim.x + threadIdx.x;
    int K = c.K[wi], N = c.N[wi];
    if (t < K * N) {
        int k = t / N, n = t % N;
        c.d[wi][(size_t)n * K + k] = f2bf(c.s[wi][t]);
    }
}

// ---------------- mean aggregation + fused epilogue ----------------
// F/4 lanes per node, ushort4 (8B) per lane. 256 threads = 8 nodes (F=128)
// or 16 nodes (F=64) per block.
// EPI: 0 = plain bf16 out; 1 = relu(agg+u+b) bf16 out; 2 = sigmoid(agg+u+b) f32 out

template <int F, int EPI>
__global__ __launch_bounds__(256)
void agg_bf(const ushort* __restrict__ in, const ushort* __restrict__ csr16,
            const int* __restrict__ row_start, const int* __restrict__ deg,
            const ushort* __restrict__ u, const float* __restrict__ bias,
            void* __restrict__ out, int nN) {
    constexpr int GPL = F / 4;                 // lanes per node
    constexpr int NPB = 256 / GPL;             // nodes per block
    int gid  = threadIdx.x / GPL;
    int li   = threadIdx.x % GPL;
    int node = blockIdx.x * NPB + gid;
    bool valid = node < nN;
    int start = valid ? row_start[node] : 0;
    int d     = valid ? deg[node] : 0;
    float a0 = 0.f, a1 = 0.f, a2 = 0.f, a3 = 0.f;

    auto gat = [&](int j) {
        int s = csr16[start + j];
        ushort4 uv = *(const ushort4*)(in + (size_t)s * F + li * 4);
        a0 += bf2f(uv.x); a1 += bf2f(uv.y); a2 += bf2f(uv.z); a3 += bf2f(uv.w);
    };

    int j = 0;
    for (; j + 8 <= d; j += 8) {
        gat(j); gat(j+1); gat(j+2); gat(j+3);
        gat(j+4); gat(j+5); gat(j+6); gat(j+7);
    }
    for (; j + 2 <= d; j += 2) { gat(j); gat(j+1); }
    for (; j < d; ++j) gat(j);

    if (!valid) return;
    float inv = 1.f / (float)(d > 0 ? d : 1);
    a0 *= inv; a1 *= inv; a2 *= inv; a3 *= inv;

    size_t o4 = (size_t)node * F + li * 4;
    if constexpr (EPI == 0) {
        ushort4 o; o.x = f2bf(a0); o.y = f2bf(a1); o.z = f2bf(a2); o.w = f2bf(a3);
        *(ushort4*)((ushort*)out + o4) = o;
    } else {
        ushort4 uv = *(const ushort4*)(u + o4);
        float4 bv = *(const float4*)(bias + li * 4);
        a0 += bf2f(uv.x) + bv.x;
        a1 += bf2f(uv.y) + bv.y;
        a2 += bf2f(uv.z) + bv.z;
        a3 += bf2f(uv.w) + bv.w;
        if constexpr (EPI == 1) {
            ushort4 o;
            o.x = f2bf(fmaxf(a0, 0.f)); o.y = f2bf(fmaxf(a1, 0.f));
            o.z = f2bf(fmaxf(a2, 0.f)); o.w = f2bf(fmaxf(a3, 0.f));
            *(ushort4*)((ushort*)out + o4) = o;
        } else {
            float4 o;
            o.x = 1.f / (1.f + __expf(-a0)); o.y = 1.f / (1.f + __expf(-a1));
            o.z = 1.f / (1.f + __expf(-a2)); o.w = 1.f / (1.f + __expf(-a3));
            *(float4*)((float*)out + o4) = o;
        }
    }
}

// ---------------- bf16 MFMA GEMM (BK=64 loop), split-output epilogue --------
// C[M,N] = act( A1@B1^T (+ A2@B2^T) (+ bias) ); col < nsplit -> C1, else C2.
// A: [M][K] bf16. B: [N][K] bf16 (pre-transposed). LDS XOR-swizzled.

template <int BM, int BN, int WM, int WN, int ACT>
__global__ __launch_bounds__(WM * WN * 64)
void mgemm(const ushort* __restrict__ A1, const ushort* __restrict__ B1, int K1,
           const ushort* __restrict__ A2, const ushort* __restrict__ B2, int K2,
           const float* __restrict__ bias,
           ushort* __restrict__ C1, int ld1,
           ushort* __restrict__ C2, int ld2, int nsplit,
           int M, int N) {
    constexpr int NT = WM * WN * 64;
    constexpr int MF = BM / (WM * 16);
    constexpr int NF = BN / (WN * 16);
    __shared__ char lds[(BM + BN) * 128];     // rows x 64 bf16
    char* As = lds;
    char* Bs = lds + BM * 128;

    const int tid  = threadIdx.x;
    const int lane = tid & 63;
    const int wid  = tid >> 6;
    const int wm   = wid % WM, wn = wid / WM;
    const int bm   = blockIdx.x * BM;
    const int bn   = blockIdx.y * BN;
    const int l15  = lane & 15;
    const int lhi  = lane >> 4;

    f32x4 acc[MF][NF] = {};

    for (int pass = 0; pass < 2; ++pass) {
        const ushort* A = pass ? A2 : A1;
        const ushort* B = pass ? B2 : B1;
        const int K = pass ? K2 : K1;
        if (A == nullptr) continue;
        for (int k0 = 0; k0 < K; k0 += 64) {
            #pragma unroll
            for (int it = 0; it < BM * 8 / NT; ++it) {       // stage A
                int flat = it * NT + tid;
                int row = flat >> 3;
                int cb = (flat & 7) * 16;
                frag v = {};
                int gr = bm + row;
                if (gr < M) v = *(const frag*)(A + (size_t)gr * K + k0 + (flat & 7) * 8);
                *(frag*)(As + row * 128 + (cb ^ ((row & 7) << 4))) = v;
            }
            #pragma unroll
            for (int it = 0; it < BN * 8 / NT; ++it) {       // stage B
                int flat = it * NT + tid;
                int row = flat >> 3;
                int cb = (flat & 7) * 16;
                frag v = *(const frag*)(B + (size_t)(bn + row) * K + k0 + (flat & 7) * 8);
                *(frag*)(Bs + row * 128 + (cb ^ ((row & 7) << 4))) = v;
            }
            __syncthreads();
            #pragma unroll
            for (int ks = 0; ks < 2; ++ks) {
                const int kb = ks * 64 + lhi * 16;
                frag a[MF], b[NF];
                #pragma unroll
                for (int mf = 0; mf < MF; ++mf) {
                    int row = wm * MF * 16 + mf * 16 + l15;
                    a[mf] = *(const frag*)(As + row * 128 + (kb ^ ((row & 7) << 4)));
                }
                #pragma unroll
                for (int nf = 0; nf < NF; ++nf) {
                    int row = wn * NF * 16 + nf * 16 + l15;
                    b[nf] = *(const frag*)(Bs + row * 128 + (kb ^ ((row & 7) << 4)));
                }
                #pragma unroll
                for (int mf = 0; mf < MF; ++mf)
                    #pragma unroll
                    for (int nf = 0; nf < NF; ++nf)
                        acc[mf][nf] = __builtin_amdgcn_mfma_f32_16x16x32_bf16(
                            a[mf], b[nf], acc[mf][nf], 0, 0, 0);
            }
            __syncthreads();
        }
    }

    #pragma unroll
    for (int mf = 0; mf < MF; ++mf) {
        #pragma unroll
        for (int r = 0; r < 4; ++r) {
            int gm = bm + wm * MF * 16 + mf * 16 + lhi * 4 + r;
            if (gm >= M) continue;
            #pragma unroll
            for (int nf = 0; nf < NF; ++nf) {
                int gn = bn + wn * NF * 16 + nf * 16 + l15;
                float v = acc[mf][nf][r];
                if (bias) v += bias[gn];
                if (ACT == 1) v = fmaxf(v, 0.f);
                ushort o = f2bf(v);
                if (gn < nsplit) C1[(size_t)gm * ld1 + gn] = o;
                else             C2[(size_t)gm * ld2 + (gn - nsplit)] = o;
            }
        }
    }
}

// ---------------------------------------------------------------------------

extern "C" void kernel_launch(void* const* d_in, const int* in_sizes, int n_in,
                              void* d_out, int out_size, void* d_ws, size_t ws_size,
                              hipStream_t stream) {
    const float* x   = (const float*)d_in[0];
    const int*   ei  = (const int*)d_in[1];
    const float* Wl1 = (const float*)d_in[2];
    const float* Wr1 = (const float*)d_in[3];
    const float* b1  = (const float*)d_in[4];
    const float* Wl2 = (const float*)d_in[5];
    const float* Wr2 = (const float*)d_in[6];
    const float* b2  = (const float*)d_in[7];
    const float* Wl3 = (const float*)d_in[8];
    const float* Wr3 = (const float*)d_in[9];
    const float* b3  = (const float*)d_in[10];

    const int M = in_sizes[0] / 128;   // 50000
    const int E = in_sizes[1] / 2;     // 800000
    const int P = (M + PSZ - 1) / PSZ; // 98 partitions
    const int* src = ei;
    const int* dst = ei + E;

    char* w = (char*)d_ws;
    auto alloc = [&](size_t bytes) -> void* {
        void* p = (void*)w;
        w += (bytes + 255) & ~(size_t)255;
        return p;
    };
    int* pcount    = (int*)alloc((size_t)PMAX * 4);
    int* pbase     = (int*)alloc((size_t)(PMAX + 1) * 4);
    int* pcursor   = (int*)alloc((size_t)PMAX * 4);
    unsigned* pairs = (unsigned*)alloc((size_t)E * 4);
    ushort* csr16  = (ushort*)alloc((size_t)E * 2);
    int* deg       = (int*)alloc((size_t)M * 4);
    int* row_start = (int*)alloc((size_t)M * 4);
    ushort* Wl1t   = (ushort*)alloc(256 * 128 * 2);       // [256][128]
    ushort* Wr1t   = (ushort*)alloc(256 * 128 * 2);       // [256][128]
    ushort* Wcat2T = (ushort*)alloc(256 * 256 * 2);       // [256][256]: Wl2|Wr2 rows
    ushort* Wcat3T = (ushort*)alloc(128 * 128 * 2);       // [128][128]: Wl3|Wr3 rows
    ushort* bufA = (ushort*)alloc((size_t)M * 128 * 2);   // x_bf -> t2 -> t3
    ushort* bufB = (ushort*)alloc((size_t)M * 128 * 2);   // aggx -> h2
    ushort* bufH = (ushort*)alloc((size_t)M * 256 * 2);   // h1
    ushort* bufC = (ushort*)alloc((size_t)M * 128 * 2);   // u2 -> u3
    (void)ws_size; (void)n_in; (void)out_size;

    ushort* x_bf = bufA; ushort* t2 = bufA; ushort* t3 = bufA;
    ushort* aggx = bufB; ushort* h2 = bufB;
    ushort* h1 = bufH;
    ushort* u2 = bufC;   ushort* u3 = bufC;

    // CSR build: only pcount needs zeroing (<=512B)
    hipMemsetAsync(pcount, 0, (size_t)PMAX * 4, stream);
    const int nchunk = (E + 4095) / 4096;     // 196
    k_pcount<<<nchunk, 256, 0, stream>>>(dst, pcount, E, P);
    k_pscan<<<1, 64, 0, stream>>>(pcount, pbase, pcursor, P);
    k_scatter<<<nchunk, 256, 0, stream>>>(src, dst, pcursor, pairs, E, P);
    k_build<<<P, 256, 0, stream>>>(pairs, pbase, deg, row_start, csr16, M);

    // converts
    k_cvt_x<<<(M * 128 / 4 + 255) / 256, 256, 0, stream>>>(x, x_bf, M * 128 / 4);
    CvtDesc cd;
    cd.s[0] = Wl1; cd.d[0] = Wl1t;             cd.K[0] = 128; cd.N[0] = 256;
    cd.s[1] = Wr1; cd.d[1] = Wr1t;             cd.K[1] = 128; cd.N[1] = 256;
    cd.s[2] = Wl2; cd.d[2] = Wcat2T;           cd.K[2] = 256; cd.N[2] = 128;
    cd.s[3] = Wr2; cd.d[3] = Wcat2T + 128*256; cd.K[3] = 256; cd.N[3] = 128;
    cd.s[4] = Wl3; cd.d[4] = Wcat3T;           cd.K[4] = 128; cd.N[4] = 64;
    cd.s[5] = Wr3; cd.d[5] = Wcat3T + 64*128;  cd.K[5] = 128; cd.N[5] = 64;
    k_cvt_w6<<<dim3(128, 6), 256, 0, stream>>>(cd);

    const int gm128 = (M + 127) / 128;        // 391
    const int ga128 = (M + 7) / 8;            // 6250 (F=128: 8 nodes/block)
    const int ga64  = (M + 15) / 16;          // 3125 (F=64: 16 nodes/block)

    // ---- layer 1: aggx = agg(x); h1 = relu(aggx@Wl1 + x@Wr1 + b1)
    agg_bf<128, 0><<<ga128, 256, 0, stream>>>(x_bf, csr16, row_start, deg,
                                              nullptr, nullptr, aggx, M);
    mgemm<128, 64, 2, 2, 1><<<dim3(gm128, 4), 256, 0, stream>>>(
        aggx, Wl1t, 128, x_bf, Wr1t, 128, b1,
        h1, 256, nullptr, 0, 256, M, 256);

    // ---- layer 2: [t2|u2] = h1@Wcat2; h2 = relu(agg(t2) + u2 + b2)
    mgemm<128, 64, 2, 2, 0><<<dim3(gm128, 4), 256, 0, stream>>>(
        h1, Wcat2T, 256, nullptr, nullptr, 0, nullptr,
        t2, 128, u2, 128, 128, M, 256);
    agg_bf<128, 1><<<ga128, 256, 0, stream>>>(t2, csr16, row_start, deg,
                                              u2, b2, h2, M);

    // ---- layer 3: [t3|u3] = h2@Wcat3; out = sigmoid(agg(t3) + u3 + b3)
    mgemm<128, 64, 2, 2, 0><<<dim3(gm128, 2), 256, 0, stream>>>(
        h2, Wcat3T, 128, nullptr, nullptr, 0, nullptr,
        t3, 64, u3, 64, 64, M, 128);
    agg_bf<64, 2><<<ga64, 256, 0, stream>>>(t3, csr16, row_start, deg,
                                            u3, b3, (float*)d_out, M);
}